// Round 9
// baseline (167.579 us; speedup 1.0000x reference)
//
#include <hip/hip_runtime.h>

// Problem constants (reference: clip_embeddings [32, 1024, 512] fp32)
#define BB 32
#define NN 1024
#define DD 512
#define KK 512            // k = N * 0.5
#define EPSF 1e-8f

#define CPB 32            // chunks (blocks) per batch for k1
#define TPB 32            // tokens per block (k1)
#define TPW 8             // tokens per wave  (k1)

__device__ __forceinline__ float wsumf(float v) {
#pragma unroll
    for (int m = 1; m < 64; m <<= 1) v += __shfl_xor(v, m, 64);
    return v;
}
__device__ __forceinline__ int wsumi(int v) {
#pragma unroll
    for (int m = 1; m < 64; m <<= 1) v += __shfl_xor(v, m, 64);
    return v;
}

// K1 (unchanged from R7, proven): norms + per-block unit-vector partial sums.
// grid = BB*CPB = 1024 blocks, 256 threads (4 waves). Each wave owns 8
// consecutive tokens; all 16 float4 loads issue up front (MLP). This is the
// only HBM-cold pass over x (64 MB).
__global__ __launch_bounds__(256, 4) void k1_norms_partials(const float* __restrict__ x,
                                                            float* __restrict__ norms,
                                                            float* __restrict__ partials) {
    int blk = blockIdx.x;
    int b = blk / CPB, c = blk % CPB;
    int tid = threadIdx.x, wave = tid >> 6, lane = tid & 63;
    int tok0 = c * TPB + wave * TPW;
    const float* base = x + (size_t)(b * NN + tok0) * DD;

    float4 xs0[TPW], xs1[TPW];
#pragma unroll
    for (int t = 0; t < TPW; ++t) {
        const float4* p = reinterpret_cast<const float4*>(base + (size_t)t * DD) + lane * 2;
        xs0[t] = p[0];
        xs1[t] = p[1];
    }

    float4 a0 = {0, 0, 0, 0}, a1 = {0, 0, 0, 0};
#pragma unroll
    for (int t = 0; t < TPW; ++t) {
        float4 v0 = xs0[t], v1 = xs1[t];
        float ssq = v0.x * v0.x + v0.y * v0.y + v0.z * v0.z + v0.w * v0.w +
                    v1.x * v1.x + v1.y * v1.y + v1.z * v1.z + v1.w * v1.w;
        ssq = wsumf(ssq);
        float nrm = sqrtf(ssq);
        if (lane == 0) norms[b * NN + tok0 + t] = nrm;
        float inv = 1.0f / fmaxf(nrm, EPSF);
        a0.x += v0.x * inv; a0.y += v0.y * inv; a0.z += v0.z * inv; a0.w += v0.w * inv;
        a1.x += v1.x * inv; a1.y += v1.y * inv; a1.z += v1.z * inv; a1.w += v1.w * inv;
    }

    __shared__ float red[4][DD];
    {
        float4* rr = reinterpret_cast<float4*>(&red[wave][lane * 8]);
        rr[0] = a0; rr[1] = a1;
    }
    __syncthreads();
#pragma unroll
    for (int i = 0; i < 2; ++i) {
        int d = tid + i * 256;
        partials[(size_t)blk * DD + d] = red[0][d] + red[1][d] + red[2][d] + red[3][d];
    }
}

// K234: one block per batch (32 blocks x 1024 threads, 16 waves).
//  (a) reduce the batch's 32 partials -> sum_unit (LDS, fixed order).
//  (b) all 1024 scores from L3-resident x -> LDS only (no global round-trip).
//      score[n] = dot(sum_unit, x_n) / (max(norm_n,eps)*N); wave w owns
//      tokens w*64..w*64+63, processed in 4-token load groups (static idx).
//  (c) rank-count selection in LDS, lax.top_k stable tie-break
//      (greater, or equal-with-lower-index), wave-parallel count.
//  (d) gather selected tokens (L2-warm: this block just read them) and write
//      out[b] ONCE — no atomics, no zeroing pass anywhere.
__global__ __launch_bounds__(1024, 4) void k234_scores_select_gather(
        const float* __restrict__ x,
        const float* __restrict__ norms,
        const float* __restrict__ partials,
        float* __restrict__ out) {
    int b = blockIdx.x;
    int tid = threadIdx.x, wave = tid >> 6, lane = tid & 63;

    __shared__ __align__(16) float su_lds[DD];    // 2 KB
    __shared__ __align__(16) float s_lds[NN];     // 4 KB
    __shared__ float nrm_lds[NN];                 // 4 KB
    __shared__ float red[16][DD];                 // 32 KB

    nrm_lds[tid] = norms[b * NN + tid];
    if (tid < DD) {
        float s = 0.f;
        const float* pb = partials + (size_t)b * CPB * DD;
#pragma unroll
        for (int cc = 0; cc < CPB; ++cc)          // fixed order: deterministic
            s += pb[(size_t)cc * DD + tid];
        su_lds[tid] = s;
    }
    __syncthreads();

    float4 su0 = reinterpret_cast<const float4*>(&su_lds[lane * 8])[0];
    float4 su1 = reinterpret_cast<const float4*>(&su_lds[lane * 8])[1];

    int tok0 = wave * 64;
    const float* base = x + (size_t)(b * NN + tok0) * DD;

    // (b) scores: 16 groups of 4 tokens (8 float4 in flight per group)
#pragma unroll
    for (int g = 0; g < 16; ++g) {
        float4 xs0[4], xs1[4];
#pragma unroll
        for (int t = 0; t < 4; ++t) {
            const float4* p = reinterpret_cast<const float4*>(
                base + (size_t)(g * 4 + t) * DD) + lane * 2;
            xs0[t] = p[0];
            xs1[t] = p[1];
        }
#pragma unroll
        for (int t = 0; t < 4; ++t) {
            float4 v0 = xs0[t], v1 = xs1[t];
            float d = v0.x * su0.x + v0.y * su0.y + v0.z * su0.z + v0.w * su0.w +
                      v1.x * su1.x + v1.y * su1.y + v1.z * su1.z + v1.w * su1.w;
            d = wsumf(d);
            if (lane == 0) {
                int n = tok0 + g * 4 + t;
                s_lds[n] = d / (fmaxf(nrm_lds[n], EPSF) * (float)NN);
            }
        }
    }
    __syncthreads();

    // (c)+(d) selection + gather
    const float4* sv = reinterpret_cast<const float4*>(s_lds);
    float4 c0 = {0, 0, 0, 0}, c1 = {0, 0, 0, 0};
#pragma unroll 4
    for (int t = 0; t < 64; ++t) {
        int n = tok0 + t;
        float my = s_lds[n];                      // broadcast: free
        int cnt = 0;
#pragma unroll
        for (int i = 0; i < 4; ++i) {
            int j4 = i * 64 + lane;               // conflict-free b128 reads
            float4 v = sv[j4];
            int j = j4 * 4;
            cnt += (v.x > my) || (v.x == my && (j + 0) < n);
            cnt += (v.y > my) || (v.y == my && (j + 1) < n);
            cnt += (v.z > my) || (v.z == my && (j + 2) < n);
            cnt += (v.w > my) || (v.w == my && (j + 3) < n);
        }
        cnt = wsumi(cnt);                         // wave-uniform rank
        if (cnt < KK) {                           // wave-uniform branch; L2-warm
            const float4* p = reinterpret_cast<const float4*>(
                base + (size_t)t * DD) + lane * 2;
            float4 v0 = p[0], v1 = p[1];
            c0.x += v0.x; c0.y += v0.y; c0.z += v0.z; c0.w += v0.w;
            c1.x += v1.x; c1.y += v1.y; c1.z += v1.z; c1.w += v1.w;
        }
    }
    {
        float4* rr = reinterpret_cast<float4*>(&red[wave][lane * 8]);
        rr[0] = c0; rr[1] = c1;
    }
    __syncthreads();
    if (tid < DD) {
        float v = 0.f;
#pragma unroll
        for (int w = 0; w < 16; ++w) v += red[w][tid];
        out[b * DD + tid] = v * (1.0f / (float)KK);   // single writer
    }
}

extern "C" void kernel_launch(void* const* d_in, const int* in_sizes, int n_in,
                              void* d_out, int out_size, void* d_ws, size_t ws_size,
                              hipStream_t stream) {
    const float* x = (const float*)d_in[0];
    float* out = (float*)d_out;

    float* ws = (float*)d_ws;
    float* partials = ws;                               // 1024*512 = 2 MB
    float* norms    = ws + BB * CPB * DD;               // BB*NN = 128 KB

    k1_norms_partials<<<dim3(BB * CPB), dim3(256), 0, stream>>>(x, norms, partials);
    k234_scores_select_gather<<<dim3(BB), dim3(1024), 0, stream>>>(x, norms, partials, out);
}